// Round 11
// baseline (159.143 us; speedup 1.0000x reference)
//
#include <hip/hip_runtime.h>
#include <hip/hip_bf16.h>
#include <stdint.h>

typedef unsigned short u16;
typedef __bf16 bf16x8 __attribute__((ext_vector_type(8)));
typedef float f32x4 __attribute__((ext_vector_type(4)));
typedef unsigned short u16x4 __attribute__((ext_vector_type(4)));

#define BK 64

__device__ inline float bf2f(u16 v) {
    return __builtin_bit_cast(float, (uint32_t)v << 16);
}
__device__ inline u16 f2bf(float v) {
    return __builtin_bit_cast(u16, (__bf16)v);
}
__device__ inline void gll16(const void* src, const char* lds_dst) {
    __builtin_amdgcn_global_load_lds(
        (const __attribute__((address_space(1))) void*)src,
        (__attribute__((address_space(3))) void*)lds_dst, 16, 0, 0);
}

// XCD-bijective remap. CONVENTION (R7): launch dim3(n_M_tiles, n_N_tiles) so
// nby == gridDim.y. by = N-tile, bx = M-tile. Same-XCD dispatch chunk sweeps
// all by for consecutive bx (A-panel L2 locality). total%8==0 required.
__device__ inline void xcd_remap(int nby, int& bx, int& by) {
    const int lin = (int)blockIdx.x + (int)blockIdx.y * (int)gridDim.x;
    const int g = lin & 7, s = lin >> 3;
    by = s % nby;
    bx = (s / nby) * 8 + g;
}

// ---------------------------------------------------------------------------
// LDS swizzle for bf16 [rows][64] tiles (128B rows): 8 granules of 16B per
// row, involution g' = g ^ (row&7), closed over 3 bits. Staging rows step
// +32, fragment rows +16 -> row&7 invariant per thread. Source pre-swizzled,
// read XORs the granule (rule #21 both-sides). R10-verified (conflicts ~0).
// ---------------------------------------------------------------------------

// ---------------------------------------------------------------------------
// GEMM2 (unchanged from R10): C[M][N] = A[M][K] @ Bt[N][K]^T, 128x128 tile,
// BK=64, m97 single-buffer, gll16 staging, swizzle, XCD remap.
// ---------------------------------------------------------------------------
template <typename CT>
__global__ __launch_bounds__(256) void gemm_bt(
    const u16* __restrict__ A, const u16* __restrict__ Bt,
    CT* __restrict__ C, int M, int N, int K)
{
    __shared__ u16 Al[128 * BK];   // 16 KiB
    __shared__ u16 Bl[128 * BK];   // 16 KiB
    int bx, by; xcd_remap((int)gridDim.y, bx, by);

    const int tid  = threadIdx.x;
    const int wave = tid >> 6;
    const int lane = tid & 63;
    const int wr   = wave >> 1;
    const int wc   = wave & 1;

    const int srow = tid >> 3;                       // 0..31
    const int sg   = (tid & 7) ^ ((tid >> 3) & 7);   // source granule
    const u16* abase = A  + (long)(bx * 128 + srow) * K + sg * 8;
    const u16* bbase = Bt + (long)(by * 128 + srow) * K + sg * 8;

    char* alds = (char*)&Al[0];
    char* blds = (char*)&Bl[0];
    const int wslot = wave * 1024;

    f32x4 acc[4][4];
#pragma unroll
    for (int i = 0; i < 4; ++i)
#pragma unroll
        for (int j = 0; j < 4; ++j) acc[i][j] = (f32x4){0.f, 0.f, 0.f, 0.f};

    const int fr  = lane & 15;
    const int cg  = lane >> 4;
    const int rx  = fr & 7;
    const int arow0 = (wr * 64 + fr) * BK;
    const int brow0 = (wc * 64 + fr) * BK;

    for (int kt = 0; kt < K; kt += BK) {
#pragma unroll
        for (int rd = 0; rd < 4; ++rd) {
            gll16(abase + kt + (long)rd * 32 * K, alds + rd * 4096 + wslot);
            gll16(bbase + kt + (long)rd * 32 * K, blds + rd * 4096 + wslot);
        }
        __syncthreads();

#pragma unroll
        for (int kk = 0; kk < 2; ++kk) {
            const int goff = (((kk << 2) + cg) ^ rx) << 3;
            bf16x8 af[4], bfg[4];
#pragma unroll
            for (int m = 0; m < 4; ++m)
                af[m] = *(const bf16x8*)&Al[arow0 + m * 16 * BK + goff];
#pragma unroll
            for (int n = 0; n < 4; ++n)
                bfg[n] = *(const bf16x8*)&Bl[brow0 + n * 16 * BK + goff];
#pragma unroll
            for (int m = 0; m < 4; ++m)
#pragma unroll
                for (int n = 0; n < 4; ++n)
                    acc[m][n] = __builtin_amdgcn_mfma_f32_16x16x32_bf16(
                        af[m], bfg[n], acc[m][n], 0, 0, 0);
        }
        __syncthreads();
    }

    const int crow = bx * 128 + wr * 64 + (lane >> 4) * 4;
    const int ccol = by * 128 + wc * 64 + (lane & 15);
#pragma unroll
    for (int m = 0; m < 4; ++m)
#pragma unroll
        for (int n = 0; n < 4; ++n)
#pragma unroll
            for (int j = 0; j < 4; ++j) {
                const long idx = (long)(crow + m * 16 + j) * N + (ccol + n * 16);
                if constexpr (__is_same(CT, float))
                    C[idx] = acc[m][n][j];
                else
                    C[idx] = f2bf(acc[m][n][j]);
            }
}

// ---------------------------------------------------------------------------
// GEMM1: 64x128 tile (R11 change: 1024 blocks = 4/CU for g1's skinny N=512).
// 4 waves as 2x2; wave tile 32x64 -> acc[2][4]. A-tile 8 KiB (2 staging
// rounds of 32 rows), B-tile 16 KiB (4 rounds). Same swizzle/involution.
// ---------------------------------------------------------------------------
__global__ __launch_bounds__(256) void gemm_bt_m64(
    const u16* __restrict__ A, const u16* __restrict__ Bt,
    u16* __restrict__ C, int M, int N, int K)
{
    __shared__ u16 Al[64 * BK];    //  8 KiB
    __shared__ u16 Bl[128 * BK];   // 16 KiB
    int bx, by; xcd_remap((int)gridDim.y, bx, by);

    const int tid  = threadIdx.x;
    const int wave = tid >> 6;
    const int lane = tid & 63;
    const int wr   = wave >> 1;    // 0..1 -> 32 rows each
    const int wc   = wave & 1;     // 0..1 -> 64 cols each

    const int srow = tid >> 3;                       // 0..31
    const int sg   = (tid & 7) ^ ((tid >> 3) & 7);
    const u16* abase = A  + (long)(bx * 64 + srow) * K + sg * 8;
    const u16* bbase = Bt + (long)(by * 128 + srow) * K + sg * 8;

    char* alds = (char*)&Al[0];
    char* blds = (char*)&Bl[0];
    const int wslot = wave * 1024;

    f32x4 acc[2][4];
#pragma unroll
    for (int i = 0; i < 2; ++i)
#pragma unroll
        for (int j = 0; j < 4; ++j) acc[i][j] = (f32x4){0.f, 0.f, 0.f, 0.f};

    // fragments: A row = wr*32 + fr + m*16 (m in 0..1); B row = wc*64 + fr
    // + n*16; granule (kk*4+cg) ^ (fr&7) — row&7 = fr&7 invariant.
    const int fr  = lane & 15;
    const int cg  = lane >> 4;
    const int rx  = fr & 7;
    const int arow0 = (wr * 32 + fr) * BK;
    const int brow0 = (wc * 64 + fr) * BK;

    for (int kt = 0; kt < K; kt += BK) {
        // A: 2 rounds (rows 0-31, 32-63); B: 4 rounds
        gll16(abase + kt,                alds + wslot);
        gll16(abase + kt + (long)32 * K, alds + 4096 + wslot);
#pragma unroll
        for (int rd = 0; rd < 4; ++rd)
            gll16(bbase + kt + (long)rd * 32 * K, blds + rd * 4096 + wslot);
        __syncthreads();

#pragma unroll
        for (int kk = 0; kk < 2; ++kk) {
            const int goff = (((kk << 2) + cg) ^ rx) << 3;
            bf16x8 af[2], bfg[4];
#pragma unroll
            for (int m = 0; m < 2; ++m)
                af[m] = *(const bf16x8*)&Al[arow0 + m * 16 * BK + goff];
#pragma unroll
            for (int n = 0; n < 4; ++n)
                bfg[n] = *(const bf16x8*)&Bl[brow0 + n * 16 * BK + goff];
#pragma unroll
            for (int m = 0; m < 2; ++m)
#pragma unroll
                for (int n = 0; n < 4; ++n)
                    acc[m][n] = __builtin_amdgcn_mfma_f32_16x16x32_bf16(
                        af[m], bfg[n], acc[m][n], 0, 0, 0);
        }
        __syncthreads();
    }

    const int crow = bx * 64 + wr * 32 + (lane >> 4) * 4;
    const int ccol = by * 128 + wc * 64 + (lane & 15);
#pragma unroll
    for (int m = 0; m < 2; ++m)
#pragma unroll
        for (int n = 0; n < 4; ++n)
#pragma unroll
            for (int j = 0; j < 4; ++j)
                C[(long)(crow + m * 16 + j) * N + (ccol + n * 16)] =
                    f2bf(acc[m][n][j]);
}

// ---------------------------------------------------------------------------
// fused 3-layer EMA scan: bf16 in/out, SCHUNK=64, LOOK=256,
// double-buffered 8-deep register prefetch.
// ---------------------------------------------------------------------------
#define SCHUNK 64
#define SLOOK  256

__device__ inline float sigmoidf_(float x) { return 1.f / (1.f + __expf(-x)); }

__global__ __launch_bounds__(256) void ema3_scan_bf(
    const u16* __restrict__ h, const float* __restrict__ log_a,
    u16* __restrict__ h3)
{
    const int t = (int)blockIdx.x * 256 + (int)threadIdx.x;  // 131072 threads
    const int e     = t & 511;
    const int b     = (t >> 9) & 3;
    const int chunk = t >> 11;           // 0..63
    const float a1 = sigmoidf_(log_a[e]);
    const float a2 = sigmoidf_(log_a[512 + e]);
    const float a3 = sigmoidf_(log_a[1024 + e]);
    const float c1 = 1.f - a1, c2 = 1.f - a2, c3 = 1.f - a3;
    const long base = ((long)b * 4096) * 512 + e;
    const int l0 = chunk * SCHUNK;
    const int ls = (l0 - SLOOK > 0) ? (l0 - SLOOK) : 0;
    const int S  = l0 + SCHUNK - ls;     // 64..320, all /16
    const u16* hp = h + base + (long)ls * 512;
    u16* op = h3 + base + (long)ls * 512;
    int gl = ls;
    float y1 = 0.f, y2 = 0.f, y3 = 0.f;

    u16 A[8], B[8];
#pragma unroll
    for (int i = 0; i < 8; ++i) A[i] = hp[(long)i * 512];
    hp += 8 * 512;

    const int nb = S >> 4;
    for (int ib = 0; ib < nb; ++ib) {
#pragma unroll
        for (int i = 0; i < 8; ++i) B[i] = hp[(long)i * 512];
        hp += 8 * 512;
#pragma unroll
        for (int i = 0; i < 8; ++i) {
            const float v = bf2f(A[i]);
            y1 = a1 * y1 + c1 * v;
            y2 = a2 * y2 + c2 * y1;
            y3 = a3 * y3 + c3 * y2;
            if (gl >= l0) *op = f2bf(y3);
            op += 512; ++gl;
        }
        // over-reads up to 8 rows past chunk end (in-bounds: h sits at
        // d_out+64MiB inside the 128MiB region; values never consumed)
#pragma unroll
        for (int i = 0; i < 8; ++i) A[i] = hp[(long)i * 512];
        hp += 8 * 512;
#pragma unroll
        for (int i = 0; i < 8; ++i) {
            const float v = bf2f(B[i]);
            y1 = a1 * y1 + c1 * v;
            y2 = a2 * y2 + c2 * y1;
            y3 = a3 * y3 + c3 * y2;
            if (gl >= l0) *op = f2bf(y3);
            op += 512; ++gl;
        }
    }
}

// ---------------------------------------------------------------------------
// x f32 -> bf16, float4 in / 8B out (HBM roofline ~30 us)
// ---------------------------------------------------------------------------
__global__ __launch_bounds__(256) void cvt_f32_to_bf16(
    const float* __restrict__ in, u16* __restrict__ out, int n4)
{
    int i = (int)blockIdx.x * 256 + (int)threadIdx.x;
    const int stride = (int)gridDim.x * 256;
    for (; i < n4; i += stride) {
        const float4 v = reinterpret_cast<const float4*>(in)[i];
        u16x4 o;
        o[0] = f2bf(v.x); o[1] = f2bf(v.y); o[2] = f2bf(v.z); o[3] = f2bf(v.w);
        reinterpret_cast<u16x4*>(out)[i] = o;
    }
}

// ---------------------------------------------------------------------------
// both weight matrices f32 -> bf16 in one launch (1M f32 each)
// ---------------------------------------------------------------------------
__global__ __launch_bounds__(256) void cvt_weights(
    const float* __restrict__ wd, const float* __restrict__ wu,
    u16* __restrict__ wd_o, u16* __restrict__ wu_o, int n4each)
{
    int i = (int)blockIdx.x * 256 + (int)threadIdx.x;
    const int stride = (int)gridDim.x * 256;
    for (; i < 2 * n4each; i += stride) {
        const float* in = (i < n4each) ? wd : wu;
        u16* out = (i < n4each) ? wd_o : wu_o;
        const int j = (i < n4each) ? i : (i - n4each);
        const float4 v = reinterpret_cast<const float4*>(in)[j];
        u16x4 o;
        o[0] = f2bf(v.x); o[1] = f2bf(v.y); o[2] = f2bf(v.z); o[3] = f2bf(v.w);
        reinterpret_cast<u16x4*>(out)[j] = o;
    }
}

// ---------------------------------------------------------------------------
// B=4, L=4096, D=2048, Di=512. Scratch plan:
//   d_out[0:64MiB)   = x_bf16     (dead before GEMM2 writes d_out)
//   d_out[64:80MiB)  = h (bf16)   (dead before GEMM2 writes d_out)
//   d_ws[0:2MiB)     = W_down bf16
//   d_ws[2:4MiB)     = W_up   bf16
//   d_ws[4:20MiB)    = h3 bf16
// ---------------------------------------------------------------------------
extern "C" void kernel_launch(void* const* d_in, const int* in_sizes, int n_in,
                              void* d_out, int out_size, void* d_ws, size_t ws_size,
                              hipStream_t stream)
{
    const float* x      = (const float*)d_in[0];
    const float* W_down = (const float*)d_in[1];
    const float* W_up   = (const float*)d_in[2];
    const float* log_a  = (const float*)d_in[3];
    float* out = (float*)d_out;

    u16*   x_bf  = (u16*)d_out;
    u16*   h_bf  = (u16*)((char*)d_out + (64u << 20));
    u16*   Wd_bf = (u16*)d_ws;
    u16*   Wu_bf = (u16*)((char*)d_ws + (2u << 20));
    u16*   h3    = (u16*)((char*)d_ws + (4u << 20));

    cvt_f32_to_bf16<<<4096, 256, 0, stream>>>(x, x_bf, (4 * 4096 * 2048) / 4);
    cvt_weights<<<512, 256, 0, stream>>>(W_down, W_up, Wd_bf, Wu_bf,
                                         (512 * 2048) / 4);

    // h = x_bf @ W_down^T  (M=16384, N=512, K=2048)
    // grid = dim3(n_M_tiles=256, n_N_tiles=4) -> 1024 blocks = 4/CU
    gemm_bt_m64<<<dim3(256, 4), 256, 0, stream>>>(
        x_bf, Wd_bf, h_bf, 16384, 512, 2048);

    // 3-layer EMA scan, bf16 in/out
    ema3_scan_bf<<<512, 256, 0, stream>>>(h_bf, log_a, h3);

    // out = h3 @ W_up^T  (M=16384, N=2048, K=512)
    // grid = dim3(n_M_tiles=128, n_N_tiles=16)
    gemm_bt<float><<<dim3(128, 16), 256, 0, stream>>>(
        h3, Wu_bf, out, 16384, 2048, 512);
}

// Round 12
// 149.880 us; speedup vs baseline: 1.0618x; 1.0618x over previous
//
#include <hip/hip_runtime.h>
#include <hip/hip_bf16.h>
#include <stdint.h>

typedef unsigned short u16;
typedef __bf16 bf16x8 __attribute__((ext_vector_type(8)));
typedef float f32x4 __attribute__((ext_vector_type(4)));
typedef unsigned short u16x4 __attribute__((ext_vector_type(4)));

__device__ inline float bf2f(u16 v) {
    return __builtin_bit_cast(float, (uint32_t)v << 16);
}
__device__ inline u16 f2bf(float v) {
    return __builtin_bit_cast(u16, (__bf16)v);
}
__device__ inline void gll16(const void* src, const char* lds_dst) {
    __builtin_amdgcn_global_load_lds(
        (const __attribute__((address_space(1))) void*)src,
        (__attribute__((address_space(3))) void*)lds_dst, 16, 0, 0);
}

// XCD-bijective remap. CONVENTION (R7): launch dim3(n_M_tiles, n_N_tiles) so
// nby == gridDim.y. by = N-tile, bx = M-tile. Same-XCD dispatch chunk sweeps
// all by for consecutive bx (A-panel L2 locality). total%8==0 required.
__device__ inline void xcd_remap(int nby, int& bx, int& by) {
    const int lin = (int)blockIdx.x + (int)blockIdx.y * (int)gridDim.x;
    const int g = lin & 7, s = lin >> 3;
    by = s % nby;
    bx = (s / nby) * 8 + g;
}

// ---------------------------------------------------------------------------
// GEMM2 (R10-verified, unchanged): C[M][N] = A[M][K] @ Bt[N][K]^T,
// 128x128 tile, BK=64, m97 single-buffer, gll16, 3-bit swizzle, XCD remap.
// ---------------------------------------------------------------------------
template <typename CT>
__global__ __launch_bounds__(256) void gemm_bt(
    const u16* __restrict__ A, const u16* __restrict__ Bt,
    CT* __restrict__ C, int M, int N, int K)
{
    __shared__ u16 Al[128 * 64];   // 16 KiB
    __shared__ u16 Bl[128 * 64];   // 16 KiB
    int bx, by; xcd_remap((int)gridDim.y, bx, by);

    const int tid  = threadIdx.x;
    const int wave = tid >> 6;
    const int lane = tid & 63;
    const int wr   = wave >> 1;
    const int wc   = wave & 1;

    const int srow = tid >> 3;                       // 0..31
    const int sg   = (tid & 7) ^ ((tid >> 3) & 7);   // source granule
    const u16* abase = A  + (long)(bx * 128 + srow) * K + sg * 8;
    const u16* bbase = Bt + (long)(by * 128 + srow) * K + sg * 8;

    char* alds = (char*)&Al[0];
    char* blds = (char*)&Bl[0];
    const int wslot = wave * 1024;

    f32x4 acc[4][4];
#pragma unroll
    for (int i = 0; i < 4; ++i)
#pragma unroll
        for (int j = 0; j < 4; ++j) acc[i][j] = (f32x4){0.f, 0.f, 0.f, 0.f};

    const int fr  = lane & 15;
    const int cg  = lane >> 4;
    const int rx  = fr & 7;
    const int arow0 = (wr * 64 + fr) * 64;
    const int brow0 = (wc * 64 + fr) * 64;

    for (int kt = 0; kt < K; kt += 64) {
#pragma unroll
        for (int rd = 0; rd < 4; ++rd) {
            gll16(abase + kt + (long)rd * 32 * K, alds + rd * 4096 + wslot);
            gll16(bbase + kt + (long)rd * 32 * K, blds + rd * 4096 + wslot);
        }
        __syncthreads();

#pragma unroll
        for (int kk = 0; kk < 2; ++kk) {
            const int goff = (((kk << 2) + cg) ^ rx) << 3;
            bf16x8 af[4], bfg[4];
#pragma unroll
            for (int m = 0; m < 4; ++m)
                af[m] = *(const bf16x8*)&Al[arow0 + m * 16 * 64 + goff];
#pragma unroll
            for (int n = 0; n < 4; ++n)
                bfg[n] = *(const bf16x8*)&Bl[brow0 + n * 16 * 64 + goff];
#pragma unroll
            for (int m = 0; m < 4; ++m)
#pragma unroll
                for (int n = 0; n < 4; ++n)
                    acc[m][n] = __builtin_amdgcn_mfma_f32_16x16x32_bf16(
                        af[m], bfg[n], acc[m][n], 0, 0, 0);
        }
        __syncthreads();
    }

    const int crow = bx * 128 + wr * 64 + (lane >> 4) * 4;
    const int ccol = by * 128 + wc * 64 + (lane & 15);
#pragma unroll
    for (int m = 0; m < 4; ++m)
#pragma unroll
        for (int n = 0; n < 4; ++n)
#pragma unroll
            for (int j = 0; j < 4; ++j) {
                const long idx = (long)(crow + m * 16 + j) * N + (ccol + n * 16);
                if constexpr (__is_same(CT, float))
                    C[idx] = acc[m][n][j];
                else
                    C[idx] = f2bf(acc[m][n][j]);
            }
}

// ---------------------------------------------------------------------------
// GEMM1: 128x128 tile, BK=128 (R12 change — drain amortization for the
// grid-limited 512-block shape; 2 blocks/CU regardless, 2x64KiB LDS fits).
// 16 iters of {16 gll16, drain, 64 MFMA}. Swizzle: 16 granules/row ->
// 4-bit involution g' = g ^ (row&15); staging rounds step +16 rows and
// fragment rows step +16 -> row&15 invariant per thread (rule #21).
// ---------------------------------------------------------------------------
__global__ __launch_bounds__(256) void gemm_bt_k128(
    const u16* __restrict__ A, const u16* __restrict__ Bt,
    u16* __restrict__ C, int M, int N, int K)
{
    __shared__ u16 Al[128 * 128];   // 32 KiB
    __shared__ u16 Bl[128 * 128];   // 32 KiB
    int bx, by; xcd_remap((int)gridDim.y, bx, by);

    const int tid  = threadIdx.x;
    const int wave = tid >> 6;
    const int lane = tid & 63;
    const int wr   = wave >> 1;
    const int wc   = wave & 1;

    // staging: 8 rounds/operand; round rd covers rows rd*16 + (t>>4);
    // thread owns granule t&15, source pre-swizzled with row&15 = (t>>4)&15
    const int srow = tid >> 4;                        // 0..15
    const int sg   = (tid & 15) ^ ((tid >> 4) & 15);  // source granule
    const u16* abase = A  + (long)(bx * 128 + srow) * K + sg * 8;
    const u16* bbase = Bt + (long)(by * 128 + srow) * K + sg * 8;

    char* alds = (char*)&Al[0];
    char* blds = (char*)&Bl[0];
    const int wslot = wave * 1024;

    f32x4 acc[4][4];
#pragma unroll
    for (int i = 0; i < 4; ++i)
#pragma unroll
        for (int j = 0; j < 4; ++j) acc[i][j] = (f32x4){0.f, 0.f, 0.f, 0.f};

    // fragment reads: row = (wr|wc)*64 + fr + m*16; k-slice kk in 0..3;
    // natural granule = kk*4 + (lane>>4); read LDS granule ^ (fr&15)
    const int fr  = lane & 15;
    const int cg  = lane >> 4;
    const int arow0 = (wr * 64 + fr) * 128;
    const int brow0 = (wc * 64 + fr) * 128;

    for (int kt = 0; kt < K; kt += 128) {
#pragma unroll
        for (int rd = 0; rd < 8; ++rd) {
            gll16(abase + kt + (long)rd * 16 * K, alds + rd * 4096 + wslot);
            gll16(bbase + kt + (long)rd * 16 * K, blds + rd * 4096 + wslot);
        }
        __syncthreads();   // drain vmcnt -> tile visible

#pragma unroll
        for (int kk = 0; kk < 4; ++kk) {
            const int goff = (((kk << 2) + cg) ^ fr) << 3;
            bf16x8 af[4], bfg[4];
#pragma unroll
            for (int m = 0; m < 4; ++m)
                af[m] = *(const bf16x8*)&Al[arow0 + m * 16 * 128 + goff];
#pragma unroll
            for (int n = 0; n < 4; ++n)
                bfg[n] = *(const bf16x8*)&Bl[brow0 + n * 16 * 128 + goff];
#pragma unroll
            for (int m = 0; m < 4; ++m)
#pragma unroll
                for (int n = 0; n < 4; ++n)
                    acc[m][n] = __builtin_amdgcn_mfma_f32_16x16x32_bf16(
                        af[m], bfg[n], acc[m][n], 0, 0, 0);
        }
        __syncthreads();   // reads done before next stage overwrites
    }

    const int crow = bx * 128 + wr * 64 + (lane >> 4) * 4;
    const int ccol = by * 128 + wc * 64 + (lane & 15);
#pragma unroll
    for (int m = 0; m < 4; ++m)
#pragma unroll
        for (int n = 0; n < 4; ++n)
#pragma unroll
            for (int j = 0; j < 4; ++j)
                C[(long)(crow + m * 16 + j) * N + (ccol + n * 16)] =
                    f2bf(acc[m][n][j]);
}

// ---------------------------------------------------------------------------
// fused 3-layer EMA scan: bf16 in/out, SCHUNK=64 (512 blocks), LOOK=256,
// double-buffered 8-deep register prefetch.
// ---------------------------------------------------------------------------
#define SCHUNK 64
#define SLOOK  256

__device__ inline float sigmoidf_(float x) { return 1.f / (1.f + __expf(-x)); }

__global__ __launch_bounds__(256) void ema3_scan_bf(
    const u16* __restrict__ h, const float* __restrict__ log_a,
    u16* __restrict__ h3)
{
    const int t = (int)blockIdx.x * 256 + (int)threadIdx.x;  // 131072 threads
    const int e     = t & 511;
    const int b     = (t >> 9) & 3;
    const int chunk = t >> 11;           // 0..63
    const float a1 = sigmoidf_(log_a[e]);
    const float a2 = sigmoidf_(log_a[512 + e]);
    const float a3 = sigmoidf_(log_a[1024 + e]);
    const float c1 = 1.f - a1, c2 = 1.f - a2, c3 = 1.f - a3;
    const long base = ((long)b * 4096) * 512 + e;
    const int l0 = chunk * SCHUNK;
    const int ls = (l0 - SLOOK > 0) ? (l0 - SLOOK) : 0;
    const int S  = l0 + SCHUNK - ls;     // 64..320, all /16
    const u16* hp = h + base + (long)ls * 512;
    u16* op = h3 + base + (long)ls * 512;
    int gl = ls;
    float y1 = 0.f, y2 = 0.f, y3 = 0.f;

    u16 A[8], B[8];
#pragma unroll
    for (int i = 0; i < 8; ++i) A[i] = hp[(long)i * 512];
    hp += 8 * 512;

    const int nb = S >> 4;
    for (int ib = 0; ib < nb; ++ib) {
#pragma unroll
        for (int i = 0; i < 8; ++i) B[i] = hp[(long)i * 512];
        hp += 8 * 512;
#pragma unroll
        for (int i = 0; i < 8; ++i) {
            const float v = bf2f(A[i]);
            y1 = a1 * y1 + c1 * v;
            y2 = a2 * y2 + c2 * y1;
            y3 = a3 * y3 + c3 * y2;
            if (gl >= l0) *op = f2bf(y3);
            op += 512; ++gl;
        }
        // over-reads up to 8 rows past chunk end (in-bounds: h sits at
        // d_out+64MiB inside the 128MiB region; values never consumed)
#pragma unroll
        for (int i = 0; i < 8; ++i) A[i] = hp[(long)i * 512];
        hp += 8 * 512;
#pragma unroll
        for (int i = 0; i < 8; ++i) {
            const float v = bf2f(B[i]);
            y1 = a1 * y1 + c1 * v;
            y2 = a2 * y2 + c2 * y1;
            y3 = a3 * y3 + c3 * y2;
            if (gl >= l0) *op = f2bf(y3);
            op += 512; ++gl;
        }
    }
}

// ---------------------------------------------------------------------------
// x f32 -> bf16, float4 in / 8B out (HBM roofline ~30 us)
// ---------------------------------------------------------------------------
__global__ __launch_bounds__(256) void cvt_f32_to_bf16(
    const float* __restrict__ in, u16* __restrict__ out, int n4)
{
    int i = (int)blockIdx.x * 256 + (int)threadIdx.x;
    const int stride = (int)gridDim.x * 256;
    for (; i < n4; i += stride) {
        const float4 v = reinterpret_cast<const float4*>(in)[i];
        u16x4 o;
        o[0] = f2bf(v.x); o[1] = f2bf(v.y); o[2] = f2bf(v.z); o[3] = f2bf(v.w);
        reinterpret_cast<u16x4*>(out)[i] = o;
    }
}

// ---------------------------------------------------------------------------
// both weight matrices f32 -> bf16 in one launch (1M f32 each)
// ---------------------------------------------------------------------------
__global__ __launch_bounds__(256) void cvt_weights(
    const float* __restrict__ wd, const float* __restrict__ wu,
    u16* __restrict__ wd_o, u16* __restrict__ wu_o, int n4each)
{
    int i = (int)blockIdx.x * 256 + (int)threadIdx.x;
    const int stride = (int)gridDim.x * 256;
    for (; i < 2 * n4each; i += stride) {
        const float* in = (i < n4each) ? wd : wu;
        u16* out = (i < n4each) ? wd_o : wu_o;
        const int j = (i < n4each) ? i : (i - n4each);
        const float4 v = reinterpret_cast<const float4*>(in)[j];
        u16x4 o;
        o[0] = f2bf(v.x); o[1] = f2bf(v.y); o[2] = f2bf(v.z); o[3] = f2bf(v.w);
        reinterpret_cast<u16x4*>(out)[j] = o;
    }
}

// ---------------------------------------------------------------------------
// B=4, L=4096, D=2048, Di=512. Scratch plan:
//   d_out[0:64MiB)   = x_bf16     (dead before GEMM2 writes d_out)
//   d_out[64:80MiB)  = h (bf16)   (dead before GEMM2 writes d_out)
//   d_ws[0:2MiB)     = W_down bf16
//   d_ws[2:4MiB)     = W_up   bf16
//   d_ws[4:20MiB)    = h3 bf16
// ---------------------------------------------------------------------------
extern "C" void kernel_launch(void* const* d_in, const int* in_sizes, int n_in,
                              void* d_out, int out_size, void* d_ws, size_t ws_size,
                              hipStream_t stream)
{
    const float* x      = (const float*)d_in[0];
    const float* W_down = (const float*)d_in[1];
    const float* W_up   = (const float*)d_in[2];
    const float* log_a  = (const float*)d_in[3];
    float* out = (float*)d_out;

    u16*   x_bf  = (u16*)d_out;
    u16*   h_bf  = (u16*)((char*)d_out + (64u << 20));
    u16*   Wd_bf = (u16*)d_ws;
    u16*   Wu_bf = (u16*)((char*)d_ws + (2u << 20));
    u16*   h3    = (u16*)((char*)d_ws + (4u << 20));

    cvt_f32_to_bf16<<<4096, 256, 0, stream>>>(x, x_bf, (4 * 4096 * 2048) / 4);
    cvt_weights<<<512, 256, 0, stream>>>(W_down, W_up, Wd_bf, Wu_bf,
                                         (512 * 2048) / 4);

    // h = x_bf @ W_down^T  (M=16384, N=512, K=2048), BK=128
    // grid = dim3(n_M_tiles=128, n_N_tiles=4)  [xcd_remap convention]
    gemm_bt_k128<<<dim3(128, 4), 256, 0, stream>>>(
        x_bf, Wd_bf, h_bf, 16384, 512, 2048);

    // 3-layer EMA scan, bf16 in/out
    ema3_scan_bf<<<512, 256, 0, stream>>>(h_bf, log_a, h3);

    // out = h3 @ W_up^T  (M=16384, N=2048, K=512), BK=64
    // grid = dim3(n_M_tiles=128, n_N_tiles=16)
    gemm_bt<float><<<dim3(128, 16), 256, 0, stream>>>(
        h3, Wu_bf, out, 16384, 2048, 512);
}